// Round 7
// baseline (572.278 us; speedup 1.0000x reference)
//
#include <hip/hip_runtime.h>
#include <hip/hip_bf16.h>
#include <hip/hip_fp16.h>

// GCN: 3 layers of  h = relu(in_norm * A_pull( (out_norm*x) @ W ) + b)
// then seg_output = (mean_n h3) @ Wp^T + bp  and  CAM = Wp @ h3^T.
// Preprocessing: bucketed CSR build, no scattered global atomics (gfx950
// atomics write through L2 at ~0.7 TB/s of 32B sectors [R1/R2/R4]).
// Dense: MFMA f16 GEMMs (LDS-staged A), fp16 gather with fdot2 accumulate.

#define HDIM 128
#define NCLS 40
#define BSH 9
#define BSZ 512          // nodes per bucket
#define KMAX 256
#define EPB 4096         // edges per scatter/count block

typedef _Float16 half8 __attribute__((ext_vector_type(8)));
typedef _Float16 h2 __attribute__((ext_vector_type(2)));
typedef float f32x4 __attribute__((ext_vector_type(4)));

#if defined(__has_builtin)
#  if __has_builtin(__builtin_amdgcn_fdot2)
#    define HAVE_FDOT2 1
#  else
#    define HAVE_FDOT2 0
#  endif
#else
#  define HAVE_FDOT2 0
#endif

// ---------------- graph preprocessing ----------------

__global__ void zero_kernel(int* __restrict__ p, int n) {
    int i = blockIdx.x * blockDim.x + threadIdx.x;
    if (i < n) p[i] = 0;
}

// per-block LDS bucket histograms (dst and src), merged with contiguous atomics
__global__ __launch_bounds__(256) void bucket_count_kernel(
        const int* __restrict__ src, const int* __restrict__ dst,
        int* __restrict__ bcnt, int* __restrict__ sbcnt, int K, int E) {
    __shared__ int lc[KMAX], ls[KMAX];
    const int tid = threadIdx.x;
    lc[tid] = 0; ls[tid] = 0;
    __syncthreads();
    const int base = blockIdx.x * EPB;
    const int lim = min(EPB, E - base);
    for (int i = tid; i < lim; i += 256) {
        atomicAdd(&lc[dst[base + i] >> BSH], 1);
        atomicAdd(&ls[src[base + i] >> BSH], 1);
    }
    __syncthreads();
    if (tid < K) {
        if (lc[tid]) atomicAdd(&bcnt[tid], lc[tid]);
        if (ls[tid]) atomicAdd(&sbcnt[tid], ls[tid]);
    }
}

// single block: exclusive scan of both bucket-count arrays (K <= 256)
__global__ __launch_bounds__(256) void bucket_scan_kernel(
        const int* __restrict__ a, const int* __restrict__ b,
        int* __restrict__ abase, int* __restrict__ bbase, int K) {
    __shared__ int ws[8];
    const int tid = threadIdx.x, lane = tid & 63, w = tid >> 6;
    int va = (tid < K) ? a[tid] : 0;
    int vb = (tid < K) ? b[tid] : 0;
    int ia = va, ib = vb;
    #pragma unroll
    for (int d = 1; d < 64; d <<= 1) {
        int oa = __shfl_up(ia, d, 64);
        int ob = __shfl_up(ib, d, 64);
        if (lane >= d) { ia += oa; ib += ob; }
    }
    if (lane == 63) { ws[w] = ia; ws[4 + w] = ib; }
    __syncthreads();
    int oa = 0, ob = 0;
    for (int j = 0; j < w; ++j) { oa += ws[j]; ob += ws[4 + j]; }
    if (tid < K) { abase[tid] = oa + ia - va; bbase[tid] = ob + ib - vb; }
    if (tid == K - 1) { abase[K] = oa + ia; bbase[K] = ob + ib; }
}

// re-count in LDS, reserve contiguous runs, write bucketed records
__global__ __launch_bounds__(256) void bucket_scatter_kernel(
        const int* __restrict__ src, const int* __restrict__ dst,
        const int* __restrict__ bbase, const int* __restrict__ sbase,
        int* __restrict__ bcur, int* __restrict__ scur,
        int2* __restrict__ dbuf, int* __restrict__ sbuf, int K, int E) {
    __shared__ int lc[KMAX], lb[KMAX], ls[KMAX], lsb[KMAX];
    const int tid = threadIdx.x;
    lc[tid] = 0; ls[tid] = 0;
    __syncthreads();
    const int base = blockIdx.x * EPB;
    const int lim = min(EPB, E - base);
    for (int i = tid; i < lim; i += 256) {
        atomicAdd(&lc[dst[base + i] >> BSH], 1);
        atomicAdd(&ls[src[base + i] >> BSH], 1);
    }
    __syncthreads();
    if (tid < K) {
        lb[tid]  = bbase[tid] + (lc[tid] ? atomicAdd(&bcur[tid], lc[tid]) : 0);
        lsb[tid] = sbase[tid] + (ls[tid] ? atomicAdd(&scur[tid], ls[tid]) : 0);
    }
    __syncthreads();
    lc[tid] = 0; ls[tid] = 0;
    __syncthreads();
    for (int i = tid; i < lim; i += 256) {
        int d = dst[base + i], s = src[base + i];
        int kd = d >> BSH, ks = s >> BSH;
        int r = atomicAdd(&lc[kd], 1);
        dbuf[lb[kd] + r] = make_int2(d, s);
        int r2 = atomicAdd(&ls[ks], 1);
        sbuf[lsb[ks] + r2] = s;
    }
}

// one block per dst-bucket: histogram -> scan -> row_ptr/in_norm -> ranks -> col
__global__ __launch_bounds__(256) void build_csr_kernel(
        const int2* __restrict__ dbuf, const int* __restrict__ bbase,
        int* __restrict__ row_ptr, float* __restrict__ in_norm,
        int* __restrict__ col, int N, int K, int E) {
    __shared__ int cnt[BSZ], lsc[BSZ];
    __shared__ int wsum[4];
    const int k = blockIdx.x, tid = threadIdx.x;
    const int node0 = k << BSH;
    const int beg = bbase[k], end = bbase[k + 1];
    cnt[tid] = 0; cnt[tid + 256] = 0;
    __syncthreads();
    for (int i = beg + tid; i < end; i += 256)
        atomicAdd(&cnt[dbuf[i].x & (BSZ - 1)], 1);
    __syncthreads();
    const int c0 = cnt[2 * tid], c1 = cnt[2 * tid + 1];
    const int s = c0 + c1;
    int incl = s;
    const int lane = tid & 63, w = tid >> 6;
    #pragma unroll
    for (int d = 1; d < 64; d <<= 1) {
        int o = __shfl_up(incl, d, 64);
        if (lane >= d) incl += o;
    }
    if (lane == 63) wsum[w] = incl;
    __syncthreads();
    int off = 0;
    for (int j = 0; j < w; ++j) off += wsum[j];
    const int excl = off + incl - s;
    lsc[2 * tid] = excl;
    lsc[2 * tid + 1] = excl + c0;
    const int n0 = node0 + 2 * tid, n1 = node0 + 2 * tid + 1;
    if (n0 < N) { row_ptr[n0] = beg + excl;      in_norm[n0] = 1.0f / sqrtf((float)max(c0, 1)); }
    if (n1 < N) { row_ptr[n1] = beg + excl + c0; in_norm[n1] = 1.0f / sqrtf((float)max(c1, 1)); }
    if (k == K - 1 && tid == 0) row_ptr[N] = E;
    __syncthreads();
    cnt[2 * tid] = 0; cnt[2 * tid + 1] = 0;
    __syncthreads();
    for (int i = beg + tid; i < end; i += 256) {
        int2 e = dbuf[i];
        int local = e.x & (BSZ - 1);
        int r = atomicAdd(&cnt[local], 1);
        col[beg + lsc[local] + r] = e.y;
    }
}

// one block per src-bucket: histogram -> out_norm
__global__ __launch_bounds__(256) void outdeg_kernel(
        const int* __restrict__ sbuf, const int* __restrict__ sbase,
        float* __restrict__ out_norm, int N) {
    __shared__ int cnt[BSZ];
    const int k = blockIdx.x, tid = threadIdx.x;
    const int beg = sbase[k], end = sbase[k + 1];
    cnt[tid] = 0; cnt[tid + 256] = 0;
    __syncthreads();
    for (int i = beg + tid; i < end; i += 256)
        atomicAdd(&cnt[sbuf[i] & (BSZ - 1)], 1);
    __syncthreads();
    const int n0 = (k << BSH) + tid, n1 = n0 + 256;
    if (n0 < N) out_norm[n0] = 1.0f / sqrtf((float)max(cnt[tid], 1));
    if (n1 < N) out_norm[n1] = 1.0f / sqrtf((float)max(cnt[tid + 256], 1));
}

// ---------------- dense compute ----------------

// WT[w][n][k] = (fp16) W_w[k][n] for w = 0..2
__global__ void convw_kernel(const float* __restrict__ W1, const float* __restrict__ W2,
                             const float* __restrict__ W3, _Float16* __restrict__ WT) {
    int i = blockIdx.x * blockDim.x + threadIdx.x;
    if (i < 3 * HDIM * HDIM) {
        int w = i >> 14, r = i & (HDIM * HDIM - 1);
        int nn = r >> 7, k = r & 127;
        const float* W = (w == 0) ? W1 : (w == 1) ? W2 : W3;
        WT[i] = (_Float16)W[k * HDIM + nn];
    }
}

// out[m,:] = fp16( (out_norm[m] * x[m,:]) @ W )  via mfma_f32_16x16x32_f16.
// A staged through LDS (coalesced loads, stride-132 pad -> 2-way = free);
// same LDS reused for the fp16 epilogue tile.
__global__ __launch_bounds__(256) void gemm_mfma_kernel(
        const float* __restrict__ x, const _Float16* __restrict__ WT,
        const float* __restrict__ out_norm, _Float16* __restrict__ out, int n) {
    __shared__ float xs[64 * 132];                       // 33 KB, also cs (fp16 64x136)
    _Float16 (*cs)[136] = (_Float16(*)[136])xs;
    const int tid = threadIdx.x;
    const int wave = tid >> 6, lane = tid & 63;
    const int quad = lane >> 4, cI = lane & 15;
    const int row0 = blockIdx.x * 64;

    // stage normalized x tile (coalesced float4)
    for (int t = tid; t < 64 * 32; t += 256) {
        int r = t >> 5, c4 = t & 31;
        int gr = row0 + r;
        float4 v = {0.f, 0.f, 0.f, 0.f};
        if (gr < n) {
            v = ((const float4*)(x + (size_t)gr * HDIM))[c4];
            float sc = out_norm[gr];
            v.x *= sc; v.y *= sc; v.z *= sc; v.w *= sc;
        }
        *(float4*)&xs[r * 132 + c4 * 4] = v;
    }
    __syncthreads();

    // A fragments from LDS: a[kc][j] = xn[m = wave*16+cI][k = kc*32 + quad*8 + j]
    const int mrow = wave * 16 + cI;
    half8 afr[4];
    #pragma unroll
    for (int kc = 0; kc < 4; ++kc) {
        float4 u = *(const float4*)&xs[mrow * 132 + kc * 32 + quad * 8];
        float4 v = *(const float4*)&xs[mrow * 132 + kc * 32 + quad * 8 + 4];
        half8 t;
        t[0] = (_Float16)u.x; t[1] = (_Float16)u.y;
        t[2] = (_Float16)u.z; t[3] = (_Float16)u.w;
        t[4] = (_Float16)v.x; t[5] = (_Float16)v.y;
        t[6] = (_Float16)v.z; t[7] = (_Float16)v.w;
        afr[kc] = t;
    }
    __syncthreads();   // all xs reads done; LDS may be reused as cs

    f32x4 acc[8];
    #pragma unroll
    for (int nt = 0; nt < 8; ++nt) acc[nt] = (f32x4){0.f, 0.f, 0.f, 0.f};

    #pragma unroll
    for (int nt = 0; nt < 8; ++nt) {
        const _Float16* wb = WT + (size_t)(nt * 16 + cI) * HDIM + quad * 8;
        #pragma unroll
        for (int kc = 0; kc < 4; ++kc) {
            half8 bfr = *(const half8*)(wb + kc * 32);
            acc[nt] = __builtin_amdgcn_mfma_f32_16x16x32_f16(afr[kc], bfr, acc[nt], 0, 0, 0);
        }
    }

    // C/D layout: col = lane&15, row = quad*4 + reg
    #pragma unroll
    for (int nt = 0; nt < 8; ++nt)
        #pragma unroll
        for (int i = 0; i < 4; ++i)
            cs[wave * 16 + quad * 4 + i][nt * 16 + cI] = (_Float16)acc[nt][i];
    __syncthreads();

    for (int t2 = tid; t2 < 64 * 16; t2 += 256) {
        int r = t2 >> 4, ss = t2 & 15;
        int gr = row0 + r;
        if (gr < n)
            *(float4*)(out + (size_t)gr * HDIM + ss * 8) = *(float4*)&cs[r][ss * 8];
    }
}

// fdot2-based accumulate of one 16-B fp16 chunk into 8 fp32 feature sums
__device__ __forceinline__ void acc16(const float4& r, float* A, float* B) {
    const h2* p = (const h2*)&r;
    const h2 lo = {(_Float16)1.0f, (_Float16)0.0f};
    const h2 hi = {(_Float16)0.0f, (_Float16)1.0f};
    #pragma unroll
    for (int q = 0; q < 4; ++q) {
#if HAVE_FDOT2
        A[q] = __builtin_amdgcn_fdot2(p[q], lo, A[q], false);
        B[q] = __builtin_amdgcn_fdot2(p[q], hi, B[q], false);
#else
        A[q] += (float)p[q][0];
        B[q] += (float)p[q][1];
#endif
    }
}

// fp16 gather: h[n,:] = relu(in_norm[n]*sum t[col[e],:] + b) — one wave/node,
// 16-lane groups x 4 edges in flight (4 gathers outstanding), fdot2 accum.
__global__ __launch_bounds__(256) void agg_h_kernel(
        const _Float16* __restrict__ t, const int* __restrict__ row_ptr,
        const int* __restrict__ col, const float* __restrict__ in_norm,
        const float* __restrict__ bias, float* __restrict__ h, int n) {
    int node = blockIdx.x * 4 + (threadIdx.x >> 6);
    if (node >= n) return;
    const int lane = threadIdx.x & 63;
    const int eg = lane >> 4;       // edge group 0..3
    const int fq = lane & 15;       // 16-B feature chunk
    const int beg = row_ptr[node], end = row_ptr[node + 1];
    float A0[4] = {}, B0[4] = {}, A1[4] = {}, B1[4] = {};
    float A2[4] = {}, B2[4] = {}, A3[4] = {}, B3[4] = {};
    for (int e = beg; e < end; e += 64) {
        int cnt = min(64, end - e);
        int ci = (lane < cnt) ? col[e + lane] : 0;
        for (int j = 0; j < cnt; j += 16) {
            int s0 = __shfl(ci, j + eg, 64);
            int s1 = __shfl(ci, j + 4 + eg, 64);
            int s2 = __shfl(ci, j + 8 + eg, 64);
            int s3 = __shfl(ci, j + 12 + eg, 64);
            float4 r0 = {0.f,0.f,0.f,0.f}, r1 = {0.f,0.f,0.f,0.f};
            float4 r2 = {0.f,0.f,0.f,0.f}, r3 = {0.f,0.f,0.f,0.f};
            if (j + eg < cnt)      r0 = ((const float4*)(t + (size_t)s0 * HDIM))[fq];
            if (j + 4 + eg < cnt)  r1 = ((const float4*)(t + (size_t)s1 * HDIM))[fq];
            if (j + 8 + eg < cnt)  r2 = ((const float4*)(t + (size_t)s2 * HDIM))[fq];
            if (j + 12 + eg < cnt) r3 = ((const float4*)(t + (size_t)s3 * HDIM))[fq];
            acc16(r0, A0, B0);
            acc16(r1, A1, B1);
            acc16(r2, A2, B2);
            acc16(r3, A3, B3);
        }
    }
    float f[8];
    #pragma unroll
    for (int q = 0; q < 4; ++q) {
        f[2 * q]     = (A0[q] + A1[q]) + (A2[q] + A3[q]);
        f[2 * q + 1] = (B0[q] + B1[q]) + (B2[q] + B3[q]);
    }
    #pragma unroll
    for (int q = 0; q < 8; ++q) f[q] += __shfl_xor(f[q], 16, 64);
    #pragma unroll
    for (int q = 0; q < 8; ++q) f[q] += __shfl_xor(f[q], 32, 64);
    if (eg == 0) {   // lanes 0..15 hold totals for features [fq*8, fq*8+8)
        float inn = in_norm[node];
        float4 b0 = ((const float4*)bias)[2 * fq];
        float4 b1 = ((const float4*)bias)[2 * fq + 1];
        float4 o0, o1;
        o0.x = fmaxf(f[0] * inn + b0.x, 0.f);
        o0.y = fmaxf(f[1] * inn + b0.y, 0.f);
        o0.z = fmaxf(f[2] * inn + b0.z, 0.f);
        o0.w = fmaxf(f[3] * inn + b0.w, 0.f);
        o1.x = fmaxf(f[4] * inn + b1.x, 0.f);
        o1.y = fmaxf(f[5] * inn + b1.y, 0.f);
        o1.z = fmaxf(f[6] * inn + b1.z, 0.f);
        o1.w = fmaxf(f[7] * inn + b1.w, 0.f);
        float4* op = (float4*)(h + (size_t)node * HDIM);
        op[2 * fq] = o0;
        op[2 * fq + 1] = o1;
    }
}

// column sums of h (for mean over nodes)
__global__ void colsum_kernel(const float* __restrict__ h, float* __restrict__ colsum, int n) {
    int c = threadIdx.x & 127;
    int rstart = blockIdx.x * 2 + (threadIdx.x >> 7);
    float s = 0.f;
    for (int r = rstart; r < n; r += gridDim.x * 2)
        s += h[(size_t)r * HDIM + c];
    atomicAdd(&colsum[c], s);
}

__global__ void seg_kernel(const float* __restrict__ colsum, const float* __restrict__ Wp,
                           const float* __restrict__ bp, float* __restrict__ segout, float inv_n) {
    int c = threadIdx.x;
    if (c < NCLS) {
        float s = 0.f;
        #pragma unroll 4
        for (int k = 0; k < HDIM; ++k) s = fmaf(colsum[k], Wp[c * HDIM + k], s);
        segout[c] = s * inv_n + bp[c];
    }
}

// CAM[c, n] = dot(Wp[c,:], h[n,:]) — 64 nodes/block, 10 classes/wave.
__global__ __launch_bounds__(256) void cam_kernel(
        const float* __restrict__ h, const float* __restrict__ Wp,
        float* __restrict__ out, int n) {
    __shared__ float hs[64][132];
    __shared__ float wp[NCLS * HDIM];
    const int tid = threadIdx.x;
    const int n0 = blockIdx.x * 64;
    for (int t = tid; t < NCLS * 32; t += 256)
        ((float4*)wp)[t] = ((const float4*)Wp)[t];
    for (int t = tid; t < 64 * 32; t += 256) {
        int r = t >> 5, c4 = t & 31;
        float4 v = {0.f, 0.f, 0.f, 0.f};
        if (n0 + r < n) v = ((const float4*)(h + (size_t)(n0 + r) * HDIM))[c4];
        *(float4*)&hs[r][c4 * 4] = v;
    }
    __syncthreads();
    const int nl = tid & 63;
    const int cb = (tid >> 6) * 10;
    float acc[10] = {};
    for (int k = 0; k < HDIM; k += 4) {
        float4 hv = *(const float4*)&hs[nl][k];
        #pragma unroll
        for (int c = 0; c < 10; ++c) {
            float4 wv = *(const float4*)&wp[(cb + c) * HDIM + k];
            acc[c] = fmaf(hv.x, wv.x, acc[c]);
            acc[c] = fmaf(hv.y, wv.y, acc[c]);
            acc[c] = fmaf(hv.z, wv.z, acc[c]);
            acc[c] = fmaf(hv.w, wv.w, acc[c]);
        }
    }
    int gn = n0 + nl;
    if (gn < n) {
        #pragma unroll
        for (int c = 0; c < 10; ++c)
            out[(size_t)(cb + c) * n + gn] = acc[c];
    }
}

// ---------------- launch ----------------

extern "C" void kernel_launch(void* const* d_in, const int* in_sizes, int n_in,
                              void* d_out, int out_size, void* d_ws, size_t ws_size,
                              hipStream_t stream) {
    const float* features = (const float*)d_in[0];
    const float* W1 = (const float*)d_in[1];
    const float* b1 = (const float*)d_in[2];
    const float* W2 = (const float*)d_in[3];
    const float* b2 = (const float*)d_in[4];
    const float* W3 = (const float*)d_in[5];
    const float* b3 = (const float*)d_in[6];
    const float* Wp = (const float*)d_in[7];
    const float* bp = (const float*)d_in[8];
    const int*   src = (const int*)d_in[9];
    const int*   dst = (const int*)d_in[10];

    const int N = in_sizes[0] / HDIM;
    const int E = in_sizes[9];
    const int K = (N + BSZ - 1) >> BSH;           // buckets (<=256)
    float* out = (float*)d_out;

    // workspace carve-up
    char* ws = (char*)d_ws;
    size_t off = 0;
    int* bcnt   = (int*)(ws + off); off += KMAX * 4;
    int* sbcnt  = (int*)(ws + off); off += KMAX * 4;
    int* bcur   = (int*)(ws + off); off += KMAX * 4;
    int* scur   = (int*)(ws + off); off += KMAX * 4;
    float* colsum = (float*)(ws + off); off += 128 * 4;
    int* bbase  = (int*)(ws + off); off += (KMAX + 1) * 4;
    int* sbase  = (int*)(ws + off); off += (KMAX + 1) * 4;
    int* row_ptr = (int*)(ws + off); off += ((size_t)N + 1) * 4; off = (off + 15) & ~(size_t)15;
    int* col_idx = (int*)(ws + off); off += (size_t)E * 4; off = (off + 15) & ~(size_t)15;
    float* out_norm = (float*)(ws + off); off += (size_t)N * 4;
    float* in_norm  = (float*)(ws + off); off += (size_t)N * 4; off = (off + 255) & ~(size_t)255;
    _Float16* WT = (_Float16*)(ws + off); off += 3 * HDIM * HDIM * 2; off = (off + 255) & ~(size_t)255;
    _Float16* Bh = (_Float16*)(ws + off); off += (size_t)N * HDIM * 2; off = (off + 255) & ~(size_t)255;
    float* F0 = (float*)(ws + off); off += (size_t)N * HDIM * 4;
    float* F1 = (float*)(ws + off); off += (size_t)N * HDIM * 4;
    (void)ws_size; (void)n_in; (void)out_size;

    // bucket scratch lives inside F1 (consumed before layer-3 agg writes F1)
    int2* dbuf = (int2*)F1;
    int*  sbuf = (int*)((char*)F1 + (size_t)E * 8);

    const int NB = (E + EPB - 1) / EPB;

    const int nzero = 4 * KMAX + 128;
    zero_kernel<<<(nzero + 255) / 256, 256, 0, stream>>>((int*)ws, nzero);
    bucket_count_kernel<<<NB, 256, 0, stream>>>(src, dst, bcnt, sbcnt, K, E);
    bucket_scan_kernel<<<1, 256, 0, stream>>>(bcnt, sbcnt, bbase, sbase, K);
    bucket_scatter_kernel<<<NB, 256, 0, stream>>>(src, dst, bbase, sbase, bcur, scur,
                                                  dbuf, sbuf, K, E);
    build_csr_kernel<<<K, 256, 0, stream>>>(dbuf, bbase, row_ptr, in_norm, col_idx, N, K, E);
    outdeg_kernel<<<K, 256, 0, stream>>>(sbuf, sbase, out_norm, N);

    convw_kernel<<<(3 * HDIM * HDIM + 255) / 256, 256, 0, stream>>>(W1, W2, W3, WT);

    const int gemm_blocks = (N + 63) / 64;
    const int agg_blocks  = (N + 3) / 4;

    // layer 1
    gemm_mfma_kernel<<<gemm_blocks, 256, 0, stream>>>(features, WT, out_norm, Bh, N);
    agg_h_kernel<<<agg_blocks, 256, 0, stream>>>(Bh, row_ptr, col_idx, in_norm, b1, F0, N);
    // layer 2
    gemm_mfma_kernel<<<gemm_blocks, 256, 0, stream>>>(F0, WT + HDIM * HDIM, out_norm, Bh, N);
    agg_h_kernel<<<agg_blocks, 256, 0, stream>>>(Bh, row_ptr, col_idx, in_norm, b2, F0, N);
    // layer 3
    gemm_mfma_kernel<<<gemm_blocks, 256, 0, stream>>>(F0, WT + 2 * HDIM * HDIM, out_norm, Bh, N);
    agg_h_kernel<<<agg_blocks, 256, 0, stream>>>(Bh, row_ptr, col_idx, in_norm, b3, F1, N);

    // head (reads h3 = F1)
    colsum_kernel<<<512, 256, 0, stream>>>(F1, colsum, N);
    seg_kernel<<<1, 64, 0, stream>>>(colsum, Wp, bp, out, 1.0f / (float)N);
    cam_kernel<<<(N + 63) / 64, 256, 0, stream>>>(F1, Wp, out + NCLS, N);
}

// Round 8
// 517.436 us; speedup vs baseline: 1.1060x; 1.1060x over previous
//
#include <hip/hip_runtime.h>
#include <hip/hip_bf16.h>
#include <hip/hip_fp16.h>

// GCN: 3 layers of  h = relu(in_norm * A_pull( (out_norm*x) @ W ) + b)
// then seg_output = (mean_n h3) @ Wp^T + bp  and  CAM = Wp @ h3^T.
// Preprocessing: bucketed CSR build, no scattered global atomics (gfx950
// atomics write through L2 at ~0.7 TB/s of 32B sectors [R1/R2/R4]).
// agg is memory-bound at its FETCH floor (~181MB = per-XCD unique rows,
// ~3.9 TB/s service) [R6/R7]. Dense: MFMA f16 GEMM (128-row tiles, fp16 LDS),
// h stored fp16 for layers 1-2, fp32 h3 for the head; colsum fused into cam.

#define HDIM 128
#define NCLS 40
#define BSH 9
#define BSZ 512          // nodes per bucket
#define KMAX 256
#define EPB 4096         // edges per scatter/count block

typedef _Float16 half8 __attribute__((ext_vector_type(8)));
typedef float f32x4 __attribute__((ext_vector_type(4)));

// ---------------- graph preprocessing ----------------

__global__ void zero_kernel(int* __restrict__ p, int n) {
    int i = blockIdx.x * blockDim.x + threadIdx.x;
    if (i < n) p[i] = 0;
}

// per-block LDS bucket histograms (dst and src), merged with contiguous atomics
__global__ __launch_bounds__(256) void bucket_count_kernel(
        const int* __restrict__ src, const int* __restrict__ dst,
        int* __restrict__ bcnt, int* __restrict__ sbcnt, int K, int E) {
    __shared__ int lc[KMAX], ls[KMAX];
    const int tid = threadIdx.x;
    lc[tid] = 0; ls[tid] = 0;
    __syncthreads();
    const int base = blockIdx.x * EPB;
    const int lim = min(EPB, E - base);
    for (int i = tid; i < lim; i += 256) {
        atomicAdd(&lc[dst[base + i] >> BSH], 1);
        atomicAdd(&ls[src[base + i] >> BSH], 1);
    }
    __syncthreads();
    if (tid < K) {
        if (lc[tid]) atomicAdd(&bcnt[tid], lc[tid]);
        if (ls[tid]) atomicAdd(&sbcnt[tid], ls[tid]);
    }
}

// single block: exclusive scan of both bucket-count arrays (K <= 256)
__global__ __launch_bounds__(256) void bucket_scan_kernel(
        const int* __restrict__ a, const int* __restrict__ b,
        int* __restrict__ abase, int* __restrict__ bbase, int K) {
    __shared__ int ws[8];
    const int tid = threadIdx.x, lane = tid & 63, w = tid >> 6;
    int va = (tid < K) ? a[tid] : 0;
    int vb = (tid < K) ? b[tid] : 0;
    int ia = va, ib = vb;
    #pragma unroll
    for (int d = 1; d < 64; d <<= 1) {
        int oa = __shfl_up(ia, d, 64);
        int ob = __shfl_up(ib, d, 64);
        if (lane >= d) { ia += oa; ib += ob; }
    }
    if (lane == 63) { ws[w] = ia; ws[4 + w] = ib; }
    __syncthreads();
    int oa = 0, ob = 0;
    for (int j = 0; j < w; ++j) { oa += ws[j]; ob += ws[4 + j]; }
    if (tid < K) { abase[tid] = oa + ia - va; bbase[tid] = ob + ib - vb; }
    if (tid == K - 1) { abase[K] = oa + ia; bbase[K] = ob + ib; }
}

// re-count in LDS, reserve contiguous runs, write bucketed records
__global__ __launch_bounds__(256) void bucket_scatter_kernel(
        const int* __restrict__ src, const int* __restrict__ dst,
        const int* __restrict__ bbase, const int* __restrict__ sbase,
        int* __restrict__ bcur, int* __restrict__ scur,
        int2* __restrict__ dbuf, int* __restrict__ sbuf, int K, int E) {
    __shared__ int lc[KMAX], lb[KMAX], ls[KMAX], lsb[KMAX];
    const int tid = threadIdx.x;
    lc[tid] = 0; ls[tid] = 0;
    __syncthreads();
    const int base = blockIdx.x * EPB;
    const int lim = min(EPB, E - base);
    for (int i = tid; i < lim; i += 256) {
        atomicAdd(&lc[dst[base + i] >> BSH], 1);
        atomicAdd(&ls[src[base + i] >> BSH], 1);
    }
    __syncthreads();
    if (tid < K) {
        lb[tid]  = bbase[tid] + (lc[tid] ? atomicAdd(&bcur[tid], lc[tid]) : 0);
        lsb[tid] = sbase[tid] + (ls[tid] ? atomicAdd(&scur[tid], ls[tid]) : 0);
    }
    __syncthreads();
    lc[tid] = 0; ls[tid] = 0;
    __syncthreads();
    for (int i = tid; i < lim; i += 256) {
        int d = dst[base + i], s = src[base + i];
        int kd = d >> BSH, ks = s >> BSH;
        int r = atomicAdd(&lc[kd], 1);
        dbuf[lb[kd] + r] = make_int2(d, s);
        int r2 = atomicAdd(&ls[ks], 1);
        sbuf[lsb[ks] + r2] = s;
    }
}

// one block per dst-bucket: histogram -> scan -> row_ptr/in_norm -> ranks -> col
__global__ __launch_bounds__(256) void build_csr_kernel(
        const int2* __restrict__ dbuf, const int* __restrict__ bbase,
        int* __restrict__ row_ptr, float* __restrict__ in_norm,
        int* __restrict__ col, int N, int K, int E) {
    __shared__ int cnt[BSZ], lsc[BSZ];
    __shared__ int wsum[4];
    const int k = blockIdx.x, tid = threadIdx.x;
    const int node0 = k << BSH;
    const int beg = bbase[k], end = bbase[k + 1];
    cnt[tid] = 0; cnt[tid + 256] = 0;
    __syncthreads();
    for (int i = beg + tid; i < end; i += 256)
        atomicAdd(&cnt[dbuf[i].x & (BSZ - 1)], 1);
    __syncthreads();
    const int c0 = cnt[2 * tid], c1 = cnt[2 * tid + 1];
    const int s = c0 + c1;
    int incl = s;
    const int lane = tid & 63, w = tid >> 6;
    #pragma unroll
    for (int d = 1; d < 64; d <<= 1) {
        int o = __shfl_up(incl, d, 64);
        if (lane >= d) incl += o;
    }
    if (lane == 63) wsum[w] = incl;
    __syncthreads();
    int off = 0;
    for (int j = 0; j < w; ++j) off += wsum[j];
    const int excl = off + incl - s;
    lsc[2 * tid] = excl;
    lsc[2 * tid + 1] = excl + c0;
    const int n0 = node0 + 2 * tid, n1 = node0 + 2 * tid + 1;
    if (n0 < N) { row_ptr[n0] = beg + excl;      in_norm[n0] = 1.0f / sqrtf((float)max(c0, 1)); }
    if (n1 < N) { row_ptr[n1] = beg + excl + c0; in_norm[n1] = 1.0f / sqrtf((float)max(c1, 1)); }
    if (k == K - 1 && tid == 0) row_ptr[N] = E;
    __syncthreads();
    cnt[2 * tid] = 0; cnt[2 * tid + 1] = 0;
    __syncthreads();
    for (int i = beg + tid; i < end; i += 256) {
        int2 e = dbuf[i];
        int local = e.x & (BSZ - 1);
        int r = atomicAdd(&cnt[local], 1);
        col[beg + lsc[local] + r] = e.y;
    }
}

// one block per src-bucket: histogram -> out_norm
__global__ __launch_bounds__(256) void outdeg_kernel(
        const int* __restrict__ sbuf, const int* __restrict__ sbase,
        float* __restrict__ out_norm, int N) {
    __shared__ int cnt[BSZ];
    const int k = blockIdx.x, tid = threadIdx.x;
    const int beg = sbase[k], end = sbase[k + 1];
    cnt[tid] = 0; cnt[tid + 256] = 0;
    __syncthreads();
    for (int i = beg + tid; i < end; i += 256)
        atomicAdd(&cnt[sbuf[i] & (BSZ - 1)], 1);
    __syncthreads();
    const int n0 = (k << BSH) + tid, n1 = n0 + 256;
    if (n0 < N) out_norm[n0] = 1.0f / sqrtf((float)max(cnt[tid], 1));
    if (n1 < N) out_norm[n1] = 1.0f / sqrtf((float)max(cnt[tid + 256], 1));
}

// ---------------- dense compute ----------------

// WT[w][n][k] = (fp16) W_w[k][n] for w = 0..2
__global__ void convw_kernel(const float* __restrict__ W1, const float* __restrict__ W2,
                             const float* __restrict__ W3, _Float16* __restrict__ WT) {
    int i = blockIdx.x * blockDim.x + threadIdx.x;
    if (i < 3 * HDIM * HDIM) {
        int w = i >> 14, r = i & (HDIM * HDIM - 1);
        int nn = r >> 7, k = r & 127;
        const float* W = (w == 0) ? W1 : (w == 1) ? W2 : W3;
        WT[i] = (_Float16)W[k * HDIM + nn];
    }
}

// out[m,:] = fp16( (out_norm[m]*x[m,:]) @ W ) via mfma_f32_16x16x32_f16.
// 128-row block, 4 waves, 2 m-tiles/wave (64 MFMA/wave). x staged to LDS as
// fp16 (stride 136 -> 2-way bank alias = free); same LDS reused for epilogue.
// IT = float (layer 1) or _Float16 (layers 2-3).
template <typename IT>
__global__ __launch_bounds__(256) void gemm_mfma_kernel(
        const IT* __restrict__ x, const _Float16* __restrict__ WT,
        const float* __restrict__ out_norm, _Float16* __restrict__ out, int n) {
    __shared__ _Float16 xh[128 * 136];          // 34.8 KB; also epilogue cs
    const int tid = threadIdx.x;
    const int wave = tid >> 6, lane = tid & 63;
    const int quad = lane >> 4, cI = lane & 15;
    const int row0 = blockIdx.x * 128;

    // stage normalized fp16 tile (8 elems / thread-iter)
    for (int t = tid; t < 128 * 16; t += 256) {
        int r = t >> 4, c8 = t & 15;
        int gr = row0 + r;
        half8 hv = {};
        if (gr < n) {
            float sc = out_norm[gr];
            if constexpr (sizeof(IT) == 2) {
                half8 v = *(const half8*)((const _Float16*)x + (size_t)gr * HDIM + c8 * 8);
                #pragma unroll
                for (int q = 0; q < 8; ++q) hv[q] = (_Float16)((float)v[q] * sc);
            } else {
                const float* xr = (const float*)x + (size_t)gr * HDIM + c8 * 8;
                float4 u = *(const float4*)xr;
                float4 v = *(const float4*)(xr + 4);
                hv[0] = (_Float16)(u.x * sc); hv[1] = (_Float16)(u.y * sc);
                hv[2] = (_Float16)(u.z * sc); hv[3] = (_Float16)(u.w * sc);
                hv[4] = (_Float16)(v.x * sc); hv[5] = (_Float16)(v.y * sc);
                hv[6] = (_Float16)(v.z * sc); hv[7] = (_Float16)(v.w * sc);
            }
        }
        *(half8*)&xh[r * 136 + c8 * 8] = hv;
    }
    __syncthreads();

    // A fragments: wave owns m-tiles {2*wave, 2*wave+1} = rows 32*wave..+31
    half8 afr[2][4];
    #pragma unroll
    for (int i = 0; i < 2; ++i) {
        int mrow = wave * 32 + i * 16 + cI;
        #pragma unroll
        for (int kc = 0; kc < 4; ++kc)
            afr[i][kc] = *(const half8*)&xh[mrow * 136 + kc * 32 + quad * 8];
    }
    __syncthreads();   // xh reads done; LDS reused as cs below

    f32x4 acc[2][8];
    #pragma unroll
    for (int i = 0; i < 2; ++i)
        #pragma unroll
        for (int nt = 0; nt < 8; ++nt) acc[i][nt] = (f32x4){0.f, 0.f, 0.f, 0.f};

    #pragma unroll
    for (int nt = 0; nt < 8; ++nt) {
        const _Float16* wb = WT + (size_t)(nt * 16 + cI) * HDIM + quad * 8;
        half8 bfr[4];
        #pragma unroll
        for (int kc = 0; kc < 4; ++kc) bfr[kc] = *(const half8*)(wb + kc * 32);
        #pragma unroll
        for (int i = 0; i < 2; ++i)
            #pragma unroll
            for (int kc = 0; kc < 4; ++kc)
                acc[i][nt] = __builtin_amdgcn_mfma_f32_16x16x32_f16(afr[i][kc], bfr[kc], acc[i][nt], 0, 0, 0);
    }

    // C/D layout: col = lane&15, row = quad*4 + reg
    _Float16 (*cs)[136] = (_Float16(*)[136])xh;
    #pragma unroll
    for (int i = 0; i < 2; ++i)
        #pragma unroll
        for (int nt = 0; nt < 8; ++nt)
            #pragma unroll
            for (int r = 0; r < 4; ++r)
                cs[wave * 32 + i * 16 + quad * 4 + r][nt * 16 + cI] = (_Float16)acc[i][nt][r];
    __syncthreads();

    for (int t = tid; t < 128 * 16; t += 256) {
        int r = t >> 4, c8 = t & 15;
        int gr = row0 + r;
        if (gr < n)
            *(float4*)(out + (size_t)gr * HDIM + c8 * 8) = *(float4*)&cs[r][c8 * 8];
    }
}

// accumulate one 16-B fp16 chunk into 8 fp32 sums
__device__ __forceinline__ void acc16(const float4& r, float* f) {
    const __half2* p = (const __half2*)&r;
    #pragma unroll
    for (int q = 0; q < 4; ++q) {
        float2 g = __half22float2(p[q]);
        f[2 * q]     += g.x;
        f[2 * q + 1] += g.y;
    }
}

// fp16 gather: h[n,:] = relu(in_norm[n]*sum t[col[e],:] + b) — one wave/node,
// 16-lane groups x 4 edges in flight. OT = _Float16 (layers 1-2) or float (h3).
template <typename OT>
__global__ __launch_bounds__(256) void agg_h_kernel(
        const _Float16* __restrict__ t, const int* __restrict__ row_ptr,
        const int* __restrict__ col, const float* __restrict__ in_norm,
        const float* __restrict__ bias, OT* __restrict__ h, int n) {
    int node = blockIdx.x * 4 + (threadIdx.x >> 6);
    if (node >= n) return;
    const int lane = threadIdx.x & 63;
    const int eg = lane >> 4;       // edge group 0..3
    const int fq = lane & 15;       // 16-B feature chunk
    const int beg = row_ptr[node], end = row_ptr[node + 1];
    float f0[8] = {}, f1[8] = {}, f2[8] = {}, f3[8] = {};
    for (int e = beg; e < end; e += 64) {
        int cnt = min(64, end - e);
        int ci = (lane < cnt) ? col[e + lane] : 0;
        for (int j = 0; j < cnt; j += 16) {
            int s0 = __shfl(ci, j + eg, 64);
            int s1 = __shfl(ci, j + 4 + eg, 64);
            int s2 = __shfl(ci, j + 8 + eg, 64);
            int s3 = __shfl(ci, j + 12 + eg, 64);
            float4 r0 = {0.f,0.f,0.f,0.f}, r1 = {0.f,0.f,0.f,0.f};
            float4 r2 = {0.f,0.f,0.f,0.f}, r3 = {0.f,0.f,0.f,0.f};
            if (j + eg < cnt)      r0 = ((const float4*)(t + (size_t)s0 * HDIM))[fq];
            if (j + 4 + eg < cnt)  r1 = ((const float4*)(t + (size_t)s1 * HDIM))[fq];
            if (j + 8 + eg < cnt)  r2 = ((const float4*)(t + (size_t)s2 * HDIM))[fq];
            if (j + 12 + eg < cnt) r3 = ((const float4*)(t + (size_t)s3 * HDIM))[fq];
            acc16(r0, f0);
            acc16(r1, f1);
            acc16(r2, f2);
            acc16(r3, f3);
        }
    }
    float f[8];
    #pragma unroll
    for (int q = 0; q < 8; ++q) f[q] = (f0[q] + f1[q]) + (f2[q] + f3[q]);
    #pragma unroll
    for (int q = 0; q < 8; ++q) f[q] += __shfl_xor(f[q], 16, 64);
    #pragma unroll
    for (int q = 0; q < 8; ++q) f[q] += __shfl_xor(f[q], 32, 64);
    if (eg == 0) {   // lanes 0..15 hold totals for features [fq*8, fq*8+8)
        float inn = in_norm[node];
        float4 b0 = ((const float4*)bias)[2 * fq];
        float4 b1 = ((const float4*)bias)[2 * fq + 1];
        float o[8];
        o[0] = fmaxf(f[0] * inn + b0.x, 0.f);
        o[1] = fmaxf(f[1] * inn + b0.y, 0.f);
        o[2] = fmaxf(f[2] * inn + b0.z, 0.f);
        o[3] = fmaxf(f[3] * inn + b0.w, 0.f);
        o[4] = fmaxf(f[4] * inn + b1.x, 0.f);
        o[5] = fmaxf(f[5] * inn + b1.y, 0.f);
        o[6] = fmaxf(f[6] * inn + b1.z, 0.f);
        o[7] = fmaxf(f[7] * inn + b1.w, 0.f);
        if constexpr (sizeof(OT) == 2) {
            half8 hv;
            #pragma unroll
            for (int q = 0; q < 8; ++q) hv[q] = (_Float16)o[q];
            *(half8*)((_Float16*)h + (size_t)node * HDIM + fq * 8) = hv;
        } else {
            float4 o0 = {o[0], o[1], o[2], o[3]};
            float4 o1 = {o[4], o[5], o[6], o[7]};
            float4* op = (float4*)((float*)h + (size_t)node * HDIM);
            op[2 * fq] = o0;
            op[2 * fq + 1] = o1;
        }
    }
}

__global__ void seg_kernel(const float* __restrict__ colsum, const float* __restrict__ Wp,
                           const float* __restrict__ bp, float* __restrict__ segout, float inv_n) {
    int c = threadIdx.x;
    if (c < NCLS) {
        float s = 0.f;
        #pragma unroll 4
        for (int k = 0; k < HDIM; ++k) s = fmaf(colsum[k], Wp[c * HDIM + k], s);
        segout[c] = s * inv_n + bp[c];
    }
}

// CAM[c, n] = dot(Wp[c,:], h[n,:]) — 64 nodes/block, 10 classes/wave.
// Fused: per-block column sums of h -> atomicAdd into colsum (for seg).
__global__ __launch_bounds__(256) void cam_kernel(
        const float* __restrict__ h, const float* __restrict__ Wp,
        float* __restrict__ out, float* __restrict__ colsum, int n) {
    __shared__ float hs[64][132];
    __shared__ float wp[NCLS * HDIM];
    const int tid = threadIdx.x;
    const int n0 = blockIdx.x * 64;
    for (int t = tid; t < NCLS * 32; t += 256)
        ((float4*)wp)[t] = ((const float4*)Wp)[t];
    for (int t = tid; t < 64 * 32; t += 256) {
        int r = t >> 5, c4 = t & 31;
        float4 v = {0.f, 0.f, 0.f, 0.f};
        if (n0 + r < n) v = ((const float4*)(h + (size_t)(n0 + r) * HDIM))[c4];
        *(float4*)&hs[r][c4 * 4] = v;
    }
    __syncthreads();
    const int nl = tid & 63;
    const int cb = (tid >> 6) * 10;
    float acc[10] = {};
    for (int k = 0; k < HDIM; k += 4) {
        float4 hv = *(const float4*)&hs[nl][k];
        #pragma unroll
        for (int c = 0; c < 10; ++c) {
            float4 wv = *(const float4*)&wp[(cb + c) * HDIM + k];
            acc[c] = fmaf(hv.x, wv.x, acc[c]);
            acc[c] = fmaf(hv.y, wv.y, acc[c]);
            acc[c] = fmaf(hv.z, wv.z, acc[c]);
            acc[c] = fmaf(hv.w, wv.w, acc[c]);
        }
    }
    int gn = n0 + nl;
    if (gn < n) {
        #pragma unroll
        for (int c = 0; c < 10; ++c)
            out[(size_t)(cb + c) * n + gn] = acc[c];
    }
    // fused column-sum (rows beyond n staged as zeros)
    if (tid < HDIM) {
        float s = 0.f;
        #pragma unroll 4
        for (int r = 0; r < 64; ++r) s += hs[r][tid];
        atomicAdd(&colsum[tid], s);
    }
}

// ---------------- launch ----------------

extern "C" void kernel_launch(void* const* d_in, const int* in_sizes, int n_in,
                              void* d_out, int out_size, void* d_ws, size_t ws_size,
                              hipStream_t stream) {
    const float* features = (const float*)d_in[0];
    const float* W1 = (const float*)d_in[1];
    const float* b1 = (const float*)d_in[2];
    const float* W2 = (const float*)d_in[3];
    const float* b2 = (const float*)d_in[4];
    const float* W3 = (const float*)d_in[5];
    const float* b3 = (const float*)d_in[6];
    const float* Wp = (const float*)d_in[7];
    const float* bp = (const float*)d_in[8];
    const int*   src = (const int*)d_in[9];
    const int*   dst = (const int*)d_in[10];

    const int N = in_sizes[0] / HDIM;
    const int E = in_sizes[9];
    const int K = (N + BSZ - 1) >> BSH;           // buckets (<=256)
    float* out = (float*)d_out;

    // workspace carve-up
    char* ws = (char*)d_ws;
    size_t off = 0;
    int* bcnt   = (int*)(ws + off); off += KMAX * 4;
    int* sbcnt  = (int*)(ws + off); off += KMAX * 4;
    int* bcur   = (int*)(ws + off); off += KMAX * 4;
    int* scur   = (int*)(ws + off); off += KMAX * 4;
    float* colsum = (float*)(ws + off); off += 128 * 4;
    int* bbase  = (int*)(ws + off); off += (KMAX + 1) * 4;
    int* sbase  = (int*)(ws + off); off += (KMAX + 1) * 4;
    int* row_ptr = (int*)(ws + off); off += ((size_t)N + 1) * 4; off = (off + 15) & ~(size_t)15;
    int* col_idx = (int*)(ws + off); off += (size_t)E * 4; off = (off + 15) & ~(size_t)15;
    float* out_norm = (float*)(ws + off); off += (size_t)N * 4;
    float* in_norm  = (float*)(ws + off); off += (size_t)N * 4; off = (off + 255) & ~(size_t)255;
    _Float16* WT = (_Float16*)(ws + off); off += 3 * HDIM * HDIM * 2; off = (off + 255) & ~(size_t)255;
    _Float16* Bh = (_Float16*)(ws + off); off += (size_t)N * HDIM * 2; off = (off + 255) & ~(size_t)255;
    _Float16* F0h = (_Float16*)(ws + off); off += (size_t)N * HDIM * 2; off = (off + 255) & ~(size_t)255;
    float* F1 = (float*)(ws + off); off += (size_t)N * HDIM * 4;
    (void)ws_size; (void)n_in; (void)out_size;

    // bucket scratch lives inside F1 (consumed before layer-3 agg writes F1)
    int2* dbuf = (int2*)F1;
    int*  sbuf = (int*)((char*)F1 + (size_t)E * 8);

    const int NB = (E + EPB - 1) / EPB;

    const int nzero = 4 * KMAX + 128;
    zero_kernel<<<(nzero + 255) / 256, 256, 0, stream>>>((int*)ws, nzero);
    bucket_count_kernel<<<NB, 256, 0, stream>>>(src, dst, bcnt, sbcnt, K, E);
    bucket_scan_kernel<<<1, 256, 0, stream>>>(bcnt, sbcnt, bbase, sbase, K);
    bucket_scatter_kernel<<<NB, 256, 0, stream>>>(src, dst, bbase, sbase, bcur, scur,
                                                  dbuf, sbuf, K, E);
    build_csr_kernel<<<K, 256, 0, stream>>>(dbuf, bbase, row_ptr, in_norm, col_idx, N, K, E);
    outdeg_kernel<<<K, 256, 0, stream>>>(sbuf, sbase, out_norm, N);

    convw_kernel<<<(3 * HDIM * HDIM + 255) / 256, 256, 0, stream>>>(W1, W2, W3, WT);

    const int gemm_blocks = (N + 127) / 128;
    const int agg_blocks  = (N + 3) / 4;

    // layer 1
    gemm_mfma_kernel<float><<<gemm_blocks, 256, 0, stream>>>(features, WT, out_norm, Bh, N);
    agg_h_kernel<_Float16><<<agg_blocks, 256, 0, stream>>>(Bh, row_ptr, col_idx, in_norm, b1, F0h, N);
    // layer 2
    gemm_mfma_kernel<_Float16><<<gemm_blocks, 256, 0, stream>>>(F0h, WT + HDIM * HDIM, out_norm, Bh, N);
    agg_h_kernel<_Float16><<<agg_blocks, 256, 0, stream>>>(Bh, row_ptr, col_idx, in_norm, b2, F0h, N);
    // layer 3 (h3 = F1, fp32 for the head)
    gemm_mfma_kernel<_Float16><<<gemm_blocks, 256, 0, stream>>>(F0h, WT + 2 * HDIM * HDIM, out_norm, Bh, N);
    agg_h_kernel<float><<<agg_blocks, 256, 0, stream>>>(Bh, row_ptr, col_idx, in_norm, b3, F1, N);

    // head: cam (with fused colsum) then seg
    cam_kernel<<<(N + 63) / 64, 256, 0, stream>>>(F1, Wp, out + NCLS, colsum, N);
    seg_kernel<<<1, 64, 0, stream>>>(colsum, Wp, bp, out, 1.0f / (float)N);
}